// Round 2
// baseline (73.833 us; speedup 1.0000x reference)
//
#include <hip/hip_runtime.h>

// GrowingSignature: truncated iterated-sums signature, levels 1..4, F=4.
// x: (32, 512, 4) f32;  out: (32, 512, 341) f32.
// out[b,t,0] = 1; out[b,t,1+word_idx] = signature of increments d_0..d_{t-1}.
// Word layout (signatory all_words order): len1 cols 1..4, len2 cols 5..20,
// len3 cols 21..84, len4 cols 85..340; word (a,b,c,e) -> 85+64a+16b+4c+e.

#define SIG_B 32
#define SIG_L 512
#define SIG_NSTEP 511
#define SIG_ROW 341

__global__ __launch_bounds__(256) void sig_scan_kernel(
    const float* __restrict__ x, float* __restrict__ out) {
    const int b = blockIdx.x;
    const int tid = threadIdx.x;

    __shared__ float dlds[SIG_NSTEP * 4];

    const float* xb = x + (size_t)b * SIG_L * 4;
    // Stage increments d[t][f] = x[t+1][f] - x[t][f] into LDS.
    for (int t = tid; t < SIG_NSTEP; t += 256) {
        float4 x0 = *(const float4*)(xb + t * 4);
        float4 x1 = *(const float4*)(xb + (t + 1) * 4);
        float4 d;
        d.x = x1.x - x0.x;
        d.y = x1.y - x0.y;
        d.z = x1.z - x0.z;
        d.w = x1.w - x0.w;
        *(float4*)(dlds + t * 4) = d;
    }
    __syncthreads();

    // Each lane owns one length-4 word (a,bb,cc,ee) and its full prefix chain.
    const int a  = tid >> 6;
    const int bb = (tid >> 4) & 3;
    const int cc = (tid >> 2) & 3;
    const int ee = tid & 3;

    float s1 = 0.f, s2 = 0.f, s3 = 0.f, s4 = 0.f;

    float* row = out + (size_t)b * SIG_L * SIG_ROW;

    // Row 0: constant-1 channel + zero signature state.
    if (tid == 0)        row[0] = 1.0f;
    if ((tid & 63) == 0) row[1 + a] = 0.f;
    if ((tid & 15) == 0) row[5 + (tid >> 4)] = 0.f;
    if ((tid & 3) == 0)  row[21 + (tid >> 2)] = 0.f;
    row[85 + tid] = 0.f;
    row += SIG_ROW;

    const float* dp = dlds;
#pragma unroll 4
    for (int t = 0; t < SIG_NSTEP; ++t) {
        const float da = dp[a];
        const float db = dp[bb];
        const float dc = dp[cc];
        const float de = dp[ee];
        dp += 4;
        // Chen update order: higher level consumes PRE-update lower level
        // (strictly-increasing-index iterated sums).
        s4 = fmaf(s3, de, s4);
        s3 = fmaf(s2, dc, s3);
        s2 = fmaf(s1, db, s2);
        s1 += da;

        if (tid == 0)        row[0] = 1.0f;
        if ((tid & 63) == 0) row[1 + a] = s1;
        if ((tid & 15) == 0) row[5 + (tid >> 4)] = s2;
        if ((tid & 3) == 0)  row[21 + (tid >> 2)] = s3;
        row[85 + tid] = s4;   // coalesced: consecutive lanes, consecutive dwords
        row += SIG_ROW;
    }
}

extern "C" void kernel_launch(void* const* d_in, const int* in_sizes, int n_in,
                              void* d_out, int out_size, void* d_ws, size_t ws_size,
                              hipStream_t stream) {
    const float* x = (const float*)d_in[0];   // (32, 512, 4) f32
    // d_in[1] (kernel tensor) is structural bookkeeping; hardcoded above.
    float* out = (float*)d_out;               // (32, 512, 341) f32
    sig_scan_kernel<<<SIG_B, 256, 0, stream>>>(x, out);
}

// Round 3
// 24.869 us; speedup vs baseline: 2.9688x; 2.9688x over previous
//
#include <hip/hip_runtime.h>

// GrowingSignature: truncated iterated-sums signature, levels 1..4, F=4.
// x: (32, 512, 4) f32;  out: (32, 512, 341) f32.
// Chunked scan: 16 chunks of 32 steps per batch, combined via Chen's identity.
// Word layout (signatory order): len1 cols 1..4, len2 cols 5..20,
// len3 cols 21..84, len4 cols 85..340; word (a,b,c,e) -> 85+64a+16b+4c+e.

#define SIG_B 32
#define SIG_L 512
#define SIG_NSTEP 511
#define SIG_ROW 341
#define SIG_CS 32            // chunk size (increments)
#define SIG_C 16             // ceil(511/32)
#define SIG_PAD 344          // padded row stride in workspace (floats)

// ---------- Kernel A: local chunk signatures ----------
__global__ __launch_bounds__(256) void sigA(const float* __restrict__ x,
                                            float* __restrict__ Lsig) {
    const int bc = blockIdx.x;
    const int b = bc / SIG_C, c = bc % SIG_C;
    const int tid = threadIdx.x;
    const int t0 = c * SIG_CS;
    const int nt = min(SIG_CS, SIG_NSTEP - t0);

    __shared__ float dlds[SIG_CS * 4];
    const float* xb = x + ((size_t)b * SIG_L + t0) * 4;
    if (tid < nt) {
        float4 x0 = *(const float4*)(xb + tid * 4);
        float4 x1 = *(const float4*)(xb + (tid + 1) * 4);
        *(float4*)(dlds + tid * 4) =
            make_float4(x1.x - x0.x, x1.y - x0.y, x1.z - x0.z, x1.w - x0.w);
    }
    __syncthreads();

    const int a = tid >> 6, bb = (tid >> 4) & 3, cc = (tid >> 2) & 3, ee = tid & 3;
    float s1 = 0.f, s2 = 0.f, s3 = 0.f, s4 = 0.f;
    const float* dp = dlds;
    for (int t = 0; t < nt; ++t) {
        const float da = dp[a], db = dp[bb], dc = dp[cc], de = dp[ee];
        dp += 4;
        s4 = fmaf(s3, de, s4);  // top level first: consumes pre-update s3
        s3 = fmaf(s2, dc, s3);
        s2 = fmaf(s1, db, s2);
        s1 += da;
    }
    float* Lr = Lsig + (size_t)bc * SIG_PAD;
    if ((tid & 63) == 0) Lr[1 + a] = s1;
    if ((tid & 15) == 0) Lr[5 + (tid >> 4)] = s2;
    if ((tid & 3) == 0)  Lr[21 + (tid >> 2)] = s3;
    Lr[85 + tid] = s4;
}

// ---------- Kernel B: sequential Chen combine -> chunk-start prefixes ----------
__global__ __launch_bounds__(256) void sigB(const float* __restrict__ Lsig,
                                            float* __restrict__ Pws) {
    const int b = blockIdx.x;
    const int tid = threadIdx.x;
    __shared__ float L[SIG_C * SIG_PAD];
    const float* Lb = Lsig + (size_t)b * SIG_C * SIG_PAD;
    for (int i = tid; i < SIG_C * SIG_PAD; i += 256) L[i] = Lb[i];
    __syncthreads();

    const int a = tid >> 6, bb = (tid >> 4) & 3, cc = (tid >> 2) & 3, ee = tid & 3;
    float p1 = 0.f, p2 = 0.f, p3 = 0.f, p4 = 0.f;
    float* Pb = Pws + (size_t)b * SIG_C * SIG_PAD;
    for (int c = 0; c < SIG_C; ++c) {
        // store prefix BEFORE chunk c
        float* Pr = Pb + c * SIG_PAD;
        if ((tid & 63) == 0) Pr[1 + a] = p1;
        if ((tid & 15) == 0) Pr[5 + (tid >> 4)] = p2;
        if ((tid & 3) == 0)  Pr[21 + (tid >> 2)] = p3;
        Pr[85 + tid] = p4;
        // Chen product: P <- P (x) L[c]
        const float* Lc = L + c * SIG_PAD;
        const float l1a = Lc[1 + a], l1b = Lc[1 + bb], l1c = Lc[1 + cc], l1e = Lc[1 + ee];
        const float l2ab = Lc[5 + 4 * a + bb], l2bc = Lc[5 + 4 * bb + cc],
                    l2ce = Lc[5 + 4 * cc + ee];
        const float l3abc = Lc[21 + 16 * a + 4 * bb + cc],
                    l3bce = Lc[21 + 16 * bb + 4 * cc + ee];
        const float l4 = Lc[85 + tid];
        p4 += p3 * l1e + p2 * l2ce + p1 * l3bce + l4;  // uses pre-update p1..p3
        p3 += p2 * l1c + p1 * l2bc + l3abc;
        p2 += p1 * l1b + l2ab;
        p1 += l1a;
    }
}

// ---------- Kernel C: per-chunk output scan with suffix chains ----------
__global__ __launch_bounds__(256) void sigC(const float* __restrict__ x,
                                            const float* __restrict__ Pws,
                                            float* __restrict__ out) {
    const int bc = blockIdx.x;
    const int b = bc / SIG_C, c = bc % SIG_C;
    const int tid = threadIdx.x;
    const int t0 = c * SIG_CS;
    const int nt = min(SIG_CS, SIG_NSTEP - t0);

    __shared__ float dlds[SIG_CS * 4];
    __shared__ float P[SIG_ROW];
    const float* xb = x + ((size_t)b * SIG_L + t0) * 4;
    if (tid < nt) {
        float4 x0 = *(const float4*)(xb + tid * 4);
        float4 x1 = *(const float4*)(xb + (tid + 1) * 4);
        *(float4*)(dlds + tid * 4) =
            make_float4(x1.x - x0.x, x1.y - x0.y, x1.z - x0.z, x1.w - x0.w);
    }
    const float* Pr = Pws + (size_t)bc * SIG_PAD;
    for (int i = tid; i < SIG_ROW; i += 256) P[i] = Pr[i];  // P[0] unused
    __syncthreads();

    const int a = tid >> 6, bb = (tid >> 4) & 3, cc = (tid >> 2) & 3, ee = tid & 3;
    const float p1 = P[1 + a];
    const float p2 = P[5 + 4 * a + bb];
    const float p3 = P[21 + 16 * a + 4 * bb + cc];
    const float p4 = P[85 + tid];

    // local suffix chains: (a,b,c,e)=s*, (b,c,e)=x*, (c,e)=v*, (e)=u1
    float s1 = 0.f, s2 = 0.f, s3 = 0.f, s4 = 0.f;
    float x1_ = 0.f, x2_ = 0.f, x3_ = 0.f;
    float v1 = 0.f, v2 = 0.f;
    float u1 = 0.f;

    float* row = out + ((size_t)b * SIG_L + (t0 + 1)) * SIG_ROW;

    if (c == 0) {  // row 0: [1, zeros]
        float* r0 = out + (size_t)b * SIG_L * SIG_ROW;
        if (tid == 0)        r0[0] = 1.0f;
        if ((tid & 63) == 0) r0[1 + a] = 0.f;
        if ((tid & 15) == 0) r0[5 + (tid >> 4)] = 0.f;
        if ((tid & 3) == 0)  r0[21 + (tid >> 2)] = 0.f;
        r0[85 + tid] = 0.f;
    }

    const float* dp = dlds;
    for (int t = 0; t < nt; ++t) {
        const float da = dp[a], db = dp[bb], dc = dp[cc], de = dp[ee];
        dp += 4;
        // update all suffix chains, top level first (pre-update lower levels)
        s4 = fmaf(s3, de, s4); s3 = fmaf(s2, dc, s3); s2 = fmaf(s1, db, s2); s1 += da;
        x3_ = fmaf(x2_, de, x3_); x2_ = fmaf(x1_, dc, x2_); x1_ += db;
        v2 = fmaf(v1, de, v2); v1 += dc;
        u1 += de;

        if (tid == 0)        row[0] = 1.0f;
        if ((tid & 63) == 0) row[1 + a] = p1 + s1;
        if ((tid & 15) == 0) row[5 + (tid >> 4)] = p2 + p1 * x1_ + s2;
        if ((tid & 3) == 0)  row[21 + (tid >> 2)] = p3 + p2 * v1 + p1 * x2_ + s3;
        row[85 + tid] = p4 + p3 * u1 + p2 * v2 + p1 * x3_ + s4;  // coalesced
        row += SIG_ROW;
    }
}

extern "C" void kernel_launch(void* const* d_in, const int* in_sizes, int n_in,
                              void* d_out, int out_size, void* d_ws, size_t ws_size,
                              hipStream_t stream) {
    const float* x = (const float*)d_in[0];   // (32, 512, 4) f32
    float* out = (float*)d_out;               // (32, 512, 341) f32
    float* Lsig = (float*)d_ws;                                   // 512*344 floats
    float* Pws  = Lsig + (size_t)SIG_B * SIG_C * SIG_PAD;         // 512*344 floats

    sigA<<<SIG_B * SIG_C, 256, 0, stream>>>(x, Lsig);
    sigB<<<SIG_B, 256, 0, stream>>>(Lsig, Pws);
    sigC<<<SIG_B * SIG_C, 256, 0, stream>>>(x, Pws, out);
}

// Round 4
// 22.203 us; speedup vs baseline: 3.3253x; 1.1201x over previous
//
#include <hip/hip_runtime.h>

// GrowingSignature: truncated iterated-sums signature, levels 1..4, F=4.
// x: (32, 512, 4) f32;  out: (32, 512, 341) f32.
// 2-kernel chunked scan: sigA computes chunk-local signatures; sigC
// redundantly Chen-combines prefixes per block (from LDS) and emits rows.
// Word layout (signatory order): len1 cols 1..4, len2 cols 5..20,
// len3 cols 21..84, len4 cols 85..340; word (a,b,c,e) -> 85+64a+16b+4c+e.

#define SIG_B 32
#define SIG_L 512
#define SIG_NSTEP 511
#define SIG_ROW 341
#define SIG_CS 32            // chunk size (increments)
#define SIG_C 16             // chunks per batch
#define SIG_PAD 344          // padded row stride in workspace (floats, %4==0)

// ---------- Kernel A: local chunk signatures ----------
__global__ __launch_bounds__(256) void sigA(const float* __restrict__ x,
                                            float* __restrict__ Lsig) {
    const int bc = blockIdx.x;
    const int b = bc / SIG_C, c = bc % SIG_C;
    const int tid = threadIdx.x;
    const int t0 = c * SIG_CS;
    const int nt = min(SIG_CS, SIG_NSTEP - t0);

    __shared__ float dlds[SIG_CS * 4];
    const float* xb = x + ((size_t)b * SIG_L + t0) * 4;
    if (tid < nt) {
        float4 x0 = *(const float4*)(xb + tid * 4);
        float4 x1 = *(const float4*)(xb + (tid + 1) * 4);
        *(float4*)(dlds + tid * 4) =
            make_float4(x1.x - x0.x, x1.y - x0.y, x1.z - x0.z, x1.w - x0.w);
    }
    __syncthreads();

    const int a = tid >> 6, bb = (tid >> 4) & 3, cc = (tid >> 2) & 3, ee = tid & 3;
    float s1 = 0.f, s2 = 0.f, s3 = 0.f, s4 = 0.f;
    const float* dp = dlds;
    for (int t = 0; t < nt; ++t) {
        const float da = dp[a], db = dp[bb], dc = dp[cc], de = dp[ee];
        dp += 4;
        s4 = fmaf(s3, de, s4);  // top level first: consumes pre-update s3
        s3 = fmaf(s2, dc, s3);
        s2 = fmaf(s1, db, s2);
        s1 += da;
    }
    float* Lr = Lsig + (size_t)bc * SIG_PAD;
    if ((tid & 63) == 0) Lr[1 + a] = s1;
    if ((tid & 15) == 0) Lr[5 + (tid >> 4)] = s2;
    if ((tid & 3) == 0)  Lr[21 + (tid >> 2)] = s3;
    Lr[85 + tid] = s4;
}

// ---------- Kernel C: per-block prefix combine + output scan ----------
__global__ __launch_bounds__(256) void sigC(const float* __restrict__ x,
                                            const float* __restrict__ Lsig,
                                            float* __restrict__ out) {
    const int bc = blockIdx.x;
    const int b = bc / SIG_C, c = bc % SIG_C;
    const int tid = threadIdx.x;
    const int t0 = c * SIG_CS;
    const int nt = min(SIG_CS, SIG_NSTEP - t0);

    __shared__ float dlds[SIG_CS * 4];
    __shared__ float L[SIG_C * SIG_PAD];

    const float* xb = x + ((size_t)b * SIG_L + t0) * 4;
    if (tid < nt) {
        float4 x0 = *(const float4*)(xb + tid * 4);
        float4 x1 = *(const float4*)(xb + (tid + 1) * 4);
        *(float4*)(dlds + tid * 4) =
            make_float4(x1.x - x0.x, x1.y - x0.y, x1.z - x0.z, x1.w - x0.w);
    }
    // Stage the c preceding chunk signatures (only what this block combines).
    {
        const float4* Lb4 = (const float4*)(Lsig + (size_t)b * SIG_C * SIG_PAD);
        float4* L4 = (float4*)L;
        const int n4 = c * (SIG_PAD / 4);
        for (int i = tid; i < n4; i += 256) L4[i] = Lb4[i];
    }
    __syncthreads();

    const int a = tid >> 6, bb = (tid >> 4) & 3, cc = (tid >> 2) & 3, ee = tid & 3;

    // Chen-combine chunks 0..c-1 -> prefix (p1..p4) for this lane's word.
    float p1 = 0.f, p2 = 0.f, p3 = 0.f, p4 = 0.f;
    for (int j = 0; j < c; ++j) {
        const float* Lc = L + j * SIG_PAD;
        const float l1a = Lc[1 + a], l1b = Lc[1 + bb], l1c = Lc[1 + cc], l1e = Lc[1 + ee];
        const float l2ab = Lc[5 + 4 * a + bb], l2bc = Lc[5 + 4 * bb + cc],
                    l2ce = Lc[5 + 4 * cc + ee];
        const float l3abc = Lc[21 + 16 * a + 4 * bb + cc],
                    l3bce = Lc[21 + 16 * bb + 4 * cc + ee];
        const float l4 = Lc[85 + tid];
        p4 += p3 * l1e + p2 * l2ce + p1 * l3bce + l4;  // uses pre-update p1..p3
        p3 += p2 * l1c + p1 * l2bc + l3abc;
        p2 += p1 * l1b + l2ab;
        p1 += l1a;
    }

    // local suffix chains: (a,b,c,e)=s*, (b,c,e)=x*, (c,e)=v*, (e)=u1
    float s1 = 0.f, s2 = 0.f, s3 = 0.f, s4 = 0.f;
    float x1_ = 0.f, x2_ = 0.f, x3_ = 0.f;
    float v1 = 0.f, v2 = 0.f;
    float u1 = 0.f;

    float* row = out + ((size_t)b * SIG_L + (t0 + 1)) * SIG_ROW;

    if (c == 0) {  // row 0: [1, zeros]
        float* r0 = out + (size_t)b * SIG_L * SIG_ROW;
        if (tid == 0)        __builtin_nontemporal_store(1.0f, r0 + 0);
        if ((tid & 63) == 0) __builtin_nontemporal_store(0.f, r0 + 1 + a);
        if ((tid & 15) == 0) __builtin_nontemporal_store(0.f, r0 + 5 + (tid >> 4));
        if ((tid & 3) == 0)  __builtin_nontemporal_store(0.f, r0 + 21 + (tid >> 2));
        __builtin_nontemporal_store(0.f, r0 + 85 + tid);
    }

    const float* dp = dlds;
    for (int t = 0; t < nt; ++t) {
        const float da = dp[a], db = dp[bb], dc = dp[cc], de = dp[ee];
        dp += 4;
        // update all suffix chains, top level first (pre-update lower levels)
        s4 = fmaf(s3, de, s4); s3 = fmaf(s2, dc, s3); s2 = fmaf(s1, db, s2); s1 += da;
        x3_ = fmaf(x2_, de, x3_); x2_ = fmaf(x1_, dc, x2_); x1_ += db;
        v2 = fmaf(v1, de, v2); v1 += dc;
        u1 += de;

        if (tid == 0)        __builtin_nontemporal_store(1.0f, row + 0);
        if ((tid & 63) == 0) __builtin_nontemporal_store(p1 + s1, row + 1 + a);
        if ((tid & 15) == 0) __builtin_nontemporal_store(p2 + p1 * x1_ + s2,
                                                         row + 5 + (tid >> 4));
        if ((tid & 3) == 0)  __builtin_nontemporal_store(p3 + p2 * v1 + p1 * x2_ + s3,
                                                         row + 21 + (tid >> 2));
        __builtin_nontemporal_store(p4 + p3 * u1 + p2 * v2 + p1 * x3_ + s4,
                                    row + 85 + tid);  // coalesced
        row += SIG_ROW;
    }
}

extern "C" void kernel_launch(void* const* d_in, const int* in_sizes, int n_in,
                              void* d_out, int out_size, void* d_ws, size_t ws_size,
                              hipStream_t stream) {
    const float* x = (const float*)d_in[0];   // (32, 512, 4) f32
    float* out = (float*)d_out;               // (32, 512, 341) f32
    float* Lsig = (float*)d_ws;               // 512 * 344 floats

    sigA<<<SIG_B * SIG_C, 256, 0, stream>>>(x, Lsig);
    sigC<<<SIG_B * SIG_C, 256, 0, stream>>>(x, Lsig, out);
}